// Round 10
// baseline (810.477 us; speedup 1.0000x reference)
//
#include <hip/hip_runtime.h>
#include <math.h>

#define KNN 20
#define NS 0.2f
#define EPSV 1e-6f
#define QK 8       // knn queries per block (2 per wave, interleaved)
#define OT 8
#define CROW 507   // 169*3, cat row stride (floats)
#define SSPLIT 8   // stats splits (== B; split s covers batch s exactly)

extern __shared__ __align__(16) float smem[];

// ---------------- transpose (B,N,3) -> (B,3,N) (layer-1 knn input) ----------------
__global__ void k_transpose(const float* __restrict__ x, float* __restrict__ xt,
                            int B, int N) {
    int i = blockIdx.x * blockDim.x + threadIdx.x;
    if (i >= B * N) return;
    int b = i / N, n = i % N;
    const float* src = x + (size_t)(b * N + n) * 3;
    float* dst = xt + (size_t)b * 3 * N + n;
    dst[0] = src[0];
    dst[(size_t)N] = src[1];
    dst[(size_t)2 * N] = src[2];
}

// ---------------- squared norms xx[b,n] over n-major X ----------------
__global__ void k_sqnorm(const float* __restrict__ X, float* __restrict__ xx,
                         int B, int N, int D, long batchStride, long sliceOff) {
    int i = blockIdx.x * blockDim.x + threadIdx.x;
    if (i >= B * N) return;
    int b = i / N, n = i % N;
    const float* p = X + (size_t)b * batchStride + sliceOff + n;
    float s = 0.f;
    for (int d = 0; d < D; ++d) {
        float v = p[(size_t)d * N];
        s += v * v;
    }
    xx[i] = s;
}

// ---------------- knn: 8 queries/block, wave handles 2 interleaved selections ----------------
// Distance: per-(q,m) fmac chain over d identical to R7/R8 -> pd bitwise identical.
// Selection: R8's iterative argmax verbatim per query, 2 queries interleaved per
// wave for 2x ILP in the shuffle-latency chains -> idx bitwise identical.
__global__ void k_knn(const float* __restrict__ X, const float* __restrict__ xx,
                      int* __restrict__ idx, int N, int D,
                      long batchStride, long sliceOff) {
    int b = blockIdx.y;
    int q0 = blockIdx.x * QK;
    int tid = threadIdx.x;
    int lane = tid & 63;
    int wave = tid >> 6;

    __shared__ __align__(16) float qf[128 * QK];   // [d][q], D <= 126
    __shared__ __align__(16) float pd[QK][1024];   // N == 1024

    const float* Xb = X + (size_t)b * batchStride + sliceOff;

    for (int t = tid; t < QK * D; t += 256) {
        int d = t >> 3, q = t & 7;
        qf[d * QK + q] = Xb[(size_t)d * N + (q0 + q)];
    }
    __syncthreads();

    float acc[8][4];
#pragma unroll
    for (int q = 0; q < 8; ++q)
#pragma unroll
        for (int c = 0; c < 4; ++c) acc[q][c] = 0.f;

    const float* mbase = Xb + 4 * tid;
#pragma unroll 3
    for (int d = 0; d < D; ++d) {
        float4 xm = *(const float4*)(mbase + (size_t)d * N);
        float4 qa = *(const float4*)(qf + d * QK);
        float4 qb = *(const float4*)(qf + d * QK + 4);
        float qv[8] = {qa.x, qa.y, qa.z, qa.w, qb.x, qb.y, qb.z, qb.w};
#pragma unroll
        for (int q = 0; q < 8; ++q) {
            acc[q][0] += qv[q] * xm.x;
            acc[q][1] += qv[q] * xm.y;
            acc[q][2] += qv[q] * xm.z;
            acc[q][3] += qv[q] * xm.w;
        }
    }

    float4 xm4 = *(const float4*)(xx + b * N + 4 * tid);    // xx for 4 m's
    float xmv[4] = {xm4.x, xm4.y, xm4.z, xm4.w};
#pragma unroll
    for (int q = 0; q < 8; ++q) {
        float xn = xx[b * N + q0 + q];
        float4 v;
        v.x = 2.f * acc[q][0] - xn - xmv[0];
        v.y = 2.f * acc[q][1] - xn - xmv[1];
        v.z = 2.f * acc[q][2] - xn - xmv[2];
        v.w = 2.f * acc[q][3] - xn - xmv[3];
        *(float4*)&pd[q][4 * tid] = v;
    }
    __syncthreads();

    // wave handles queries (q0+wave) and (q0+wave+4), interleaved
    float vA[16], vB[16];
#pragma unroll
    for (int t = 0; t < 16; ++t) {
        vA[t] = pd[wave][t * 64 + lane];
        vB[t] = pd[wave + 4][t * 64 + lane];
    }

    long outA = ((long)b * N + q0 + wave) * KNN;
    long outB = ((long)b * N + q0 + wave + 4) * KNN;
    for (int it = 0; it < KNN; ++it) {
        float bvA = vA[0]; int biA = lane;
        float bvB = vB[0]; int biB = lane;
#pragma unroll
        for (int t = 1; t < 16; ++t) {
            if (vA[t] > bvA) { bvA = vA[t]; biA = t * 64 + lane; }
            if (vB[t] > bvB) { bvB = vB[t]; biB = t * 64 + lane; }
        }
#pragma unroll
        for (int off = 32; off >= 1; off >>= 1) {
            float ovA = __shfl_xor(bvA, off, 64);
            int oiA = __shfl_xor(biA, off, 64);
            float ovB = __shfl_xor(bvB, off, 64);
            int oiB = __shfl_xor(biB, off, 64);
            if (ovA > bvA || (ovA == bvA && oiA < biA)) { bvA = ovA; biA = oiA; }
            if (ovB > bvB || (ovB == bvB && oiB < biB)) { bvB = ovB; biB = oiB; }
        }
        if (lane == 0) {
            idx[outA + it] = biA;
            idx[outB + it] = biB;
        }
#pragma unroll
        for (int t = 0; t < 16; ++t) {
            if (biA == t * 64 + lane) vA[t] = -INFINITY;
            if (biB == t * 64 + lane) vB[t] = -INFINITY;
        }
    }
}

// ---------------- LDS-staged point-major pair matmul ----------------
__global__ void k_matmul_pair_lds(const float* __restrict__ X, const float* __restrict__ W,
                                  const float* __restrict__ Dw,
                                  float* __restrict__ U, float* __restrict__ V,
                                  float* __restrict__ UD, float* __restrict__ VD,
                                  int C, int Co, int CoP, int TILE,
                                  int rowStride, int colOff) {
    const int CP = C * CoP;
    float* wts = smem;            // 4*CP: [WA | WB-WA | DA | DB-DA], each [c][o]
    float* xs = smem + 4 * CP;    // TILE * C * 3

    int tid = threadIdx.x;
    int bn0 = blockIdx.x * TILE;  // flattened b*N+n base
    int C3 = C * 3;

    // zero padded o-lanes
    int npad = CoP - Co;
    if (npad) {
        for (int t = tid; t < 4 * C * npad; t += 256) {
            int q = t / npad, oo = Co + t % npad;
            int mat = q / C, c = q % C;
            wts[mat * CP + c * CoP + oo] = 0.f;
        }
    }
    // stage raw weights (coalesced global reads, LDS transpose writes)
    int twoCC = 2 * C * Co;
    for (int t = tid; t < twoCC; t += 256) {
        int o = t / (2 * C), c = t % (2 * C);
        float w = W[t], dw = Dw[t];
        if (c < C) {
            wts[c * CoP + o] = w;
            wts[2 * CP + c * CoP + o] = dw;
        } else {
            wts[CP + (c - C) * CoP + o] = w;
            wts[3 * CP + (c - C) * CoP + o] = dw;
        }
    }
    // stage point rows (coalesced)
    for (int t = tid; t < TILE * C3; t += 256) {
        int p = t / C3, cc = t % C3;
        xs[t] = X[(size_t)(bn0 + p) * rowStride + colOff + cc];
    }
    __syncthreads();
    // WB -= WA, DB -= DA in place
    for (int t = tid; t < CP; t += 256) {
        wts[CP + t] -= wts[t];
        wts[3 * CP + t] -= wts[2 * CP + t];
    }
    __syncthreads();

    int GPP = CoP >> 2;
    int items = TILE * GPP;
    for (int e = tid; e < items; e += 256) {
        int p = e / GPP, og = e - p * GPP;
        int o0 = og * 4;
        const float* xr = xs + p * C3;

        float aU[4][3], aV[4][3], aDu[4][3], aDv[4][3];
#pragma unroll
        for (int i = 0; i < 4; ++i)
#pragma unroll
            for (int j = 0; j < 3; ++j) {
                aU[i][j] = 0.f; aV[i][j] = 0.f; aDu[i][j] = 0.f; aDv[i][j] = 0.f;
            }

        for (int c = 0; c < C; ++c) {
            float x0 = xr[c * 3], x1 = xr[c * 3 + 1], x2 = xr[c * 3 + 2];
            const float* wp = wts + c * CoP + o0;
            float4 wa4 = *(const float4*)(wp);
            float4 wb4 = *(const float4*)(wp + CP);
            float4 da4 = *(const float4*)(wp + 2 * CP);
            float4 db4 = *(const float4*)(wp + 3 * CP);
            float wav[4] = {wa4.x, wa4.y, wa4.z, wa4.w};
            float wbv[4] = {wb4.x, wb4.y, wb4.z, wb4.w};
            float dav[4] = {da4.x, da4.y, da4.z, da4.w};
            float dbv[4] = {db4.x, db4.y, db4.z, db4.w};
#pragma unroll
            for (int i = 0; i < 4; ++i) {
                aU[i][0] += wav[i] * x0; aU[i][1] += wav[i] * x1; aU[i][2] += wav[i] * x2;
                aV[i][0] += wbv[i] * x0; aV[i][1] += wbv[i] * x1; aV[i][2] += wbv[i] * x2;
                aDu[i][0] += dav[i] * x0; aDu[i][1] += dav[i] * x1; aDu[i][2] += dav[i] * x2;
                aDv[i][0] += dbv[i] * x0; aDv[i][1] += dbv[i] * x1; aDv[i][2] += dbv[i] * x2;
            }
        }

        size_t base = ((size_t)(bn0 + p) * Co + o0) * 3;
#pragma unroll
        for (int i = 0; i < 4; ++i) {
            int o = o0 + i;
            if (o < Co) {
                size_t off = base + (size_t)i * 3;
                U[off] = aU[i][0]; U[off + 1] = aU[i][1]; U[off + 2] = aU[i][2];
                V[off] = aV[i][0]; V[off + 1] = aV[i][1]; V[off + 2] = aV[i][2];
                UD[off] = aDu[i][0]; UD[off + 1] = aDu[i][1]; UD[off + 2] = aDu[i][2];
                VD[off] = aDv[i][0]; VD[off + 1] = aDv[i][1]; VD[off + 2] = aDv[i][2];
            }
        }
    }
}

// ---------------- BN stats stage A (deterministic, R5 order + LDS staging) ----------------
__global__ void k_stats_edge_det(const float* __restrict__ U, const float* __restrict__ V,
                                 const int* __restrict__ idx, float* __restrict__ partials,
                                 int N, int Co, int BN) {
    int o = blockIdx.x;
    int s = blockIdx.y;
    int tid = threadIdx.x;
    int P = BN / SSPLIT;      // == N == 1024
    int g0 = s * P;

    __shared__ float Ush[3072];   // N * 3 (channel-o vectors for batch s)
    __shared__ float r1[256], r2[256];

    for (int t = tid; t < P; t += 256) {
        const float* Ur = U + ((size_t)(g0 + t) * Co + o) * 3;
        Ush[t * 3 + 0] = Ur[0];
        Ush[t * 3 + 1] = Ur[1];
        Ush[t * 3 + 2] = Ur[2];
    }
    __syncthreads();

    float s1 = 0.f, s2 = 0.f;
    for (int pl = tid; pl < P; pl += 256) {
        int g = g0 + pl;                       // flattened b*N+n
        const float* Vr = V + ((size_t)g * Co + o) * 3;
        float v0 = Vr[0], v1 = Vr[1], v2 = Vr[2];
        const int* ip = idx + (size_t)g * KNN;
        for (int kk = 0; kk < KNN; ++kk) {
            const float* Ur = Ush + ip[kk] * 3;   // idx is batch-local
            float p0 = Ur[0] + v0;
            float p1 = Ur[1] + v1;
            float p2 = Ur[2] + v2;
            float nm = sqrtf(p0 * p0 + p1 * p1 + p2 * p2) + EPSV;
            s1 += nm;
            s2 += nm * nm;
        }
    }
    r1[tid] = s1; r2[tid] = s2;
    __syncthreads();
    for (int st = 128; st > 0; st >>= 1) {
        if (tid < st) { r1[tid] += r1[tid + st]; r2[tid] += r2[tid + st]; }
        __syncthreads();
    }
    if (tid == 0) {
        partials[(o * SSPLIT + s) * 2] = r1[0];
        partials[(o * SSPLIT + s) * 2 + 1] = r2[0];
    }
}

// ---------------- BN stats stage B: fixed-order partial sum -> (mu, inv_std) ----------------
__global__ void k_stats_reduce(const float* __restrict__ partials, float* __restrict__ mv,
                               int Co, float cnt) {
    int o = blockIdx.x * 256 + threadIdx.x;
    if (o >= Co) return;
    float s1 = 0.f, s2 = 0.f;
    for (int s = 0; s < SSPLIT; ++s) {
        s1 += partials[(o * SSPLIT + s) * 2];
        s2 += partials[(o * SSPLIT + s) * 2 + 1];
    }
    float mu = s1 / cnt;
    float var = s2 / cnt - mu * mu;
    mv[2 * o] = mu;
    mv[2 * o + 1] = rsqrtf(var + 1e-5f);
}

// ---------------- BN + dir leaky + mean-pool, point-major: thread per (b,n,o) ----------------
__global__ void k_final_edge_p(const float* __restrict__ U, const float* __restrict__ V,
                               const float* __restrict__ UD, const float* __restrict__ VD,
                               const int* __restrict__ idx, const float* __restrict__ mv,
                               const float* __restrict__ gamma, const float* __restrict__ beta,
                               float* __restrict__ catp,
                               int N, int Co, int colOff, int total) {
    int g = blockIdx.x * 256 + threadIdx.x;
    if (g >= total) return;
    int o = g % Co;
    int r = g / Co;
    int n = r % N;
    int b = r / N;

    float mu = mv[2 * o];
    float inv = mv[2 * o + 1];
    float gmm = gamma[o], bt = beta[o];

    size_t ctr = ((size_t)(b * N + n) * Co + o) * 3;
    float v0 = V[ctr], v1 = V[ctr + 1], v2 = V[ctr + 2];
    float w0 = VD[ctr], w1 = VD[ctr + 1], w2 = VD[ctr + 2];
    const int* ip = idx + ((size_t)b * N + n) * KNN;

    float a0 = 0.f, a1 = 0.f, a2 = 0.f;
    for (int kk = 0; kk < KNN; ++kk) {
        int m = ip[kk];
        size_t nb = ((size_t)(b * N + m) * Co + o) * 3;
        float p0 = U[nb] + v0;
        float p1 = U[nb + 1] + v1;
        float p2 = U[nb + 2] + v2;
        float nm = sqrtf(p0 * p0 + p1 * p1 + p2 * p2) + EPSV;
        float nbn = (nm - mu) * inv * gmm + bt;
        float sc = nbn / nm;
        p0 *= sc; p1 *= sc; p2 *= sc;
        float d0 = UD[nb] + w0;
        float d1 = UD[nb + 1] + w1;
        float d2 = UD[nb + 2] + w2;
        float dot = p0 * d0 + p1 * d1 + p2 * d2;
        if (dot >= 0.f) {
            a0 += p0; a1 += p1; a2 += p2;
        } else {
            float f = dot / (d0 * d0 + d1 * d1 + d2 * d2 + EPSV);
            a0 += NS * p0 + (1.f - NS) * (p0 - f * d0);
            a1 += NS * p1 + (1.f - NS) * (p1 - f * d1);
            a2 += NS * p2 + (1.f - NS) * (p2 - f * d2);
        }
    }
    const float invk = 1.f / (float)KNN;
    float* outp = catp + (size_t)(b * N + n) * CROW + colOff + o * 3;
    outp[0] = a0 * invk;
    outp[1] = a1 * invk;
    outp[2] = a2 * invk;
}

// ---------------- cat_p slice -> cat_n slice (LDS tiled transpose) ----------------
__global__ void k_transpose_cat(const float* __restrict__ catp, float* __restrict__ catn,
                                int N, int c0, int CC) {
    __shared__ float tile[32][33];
    int b = blockIdx.z;
    int n0 = blockIdx.x * 32;
    int cb = blockIdx.y * 32;
    int tid = threadIdx.x;
    int tx = tid & 31, ty = tid >> 5;   // 32 x 8

#pragma unroll
    for (int rr = 0; rr < 4; ++rr) {
        int nl = ty + rr * 8;
        int c = cb + tx;
        if (c < CC)
            tile[nl][tx] = catp[(size_t)(b * N + n0 + nl) * CROW + c0 + c];
    }
    __syncthreads();
#pragma unroll
    for (int rr = 0; rr < 4; ++rr) {
        int cl = ty + rr * 8;
        int c = cb + cl;
        if (c < CC)
            catn[(size_t)b * CROW * N + (size_t)(c0 + c) * N + n0 + tx] = tile[tx][cl];
    }
}

// ---------------- plain matmul (layer 5, n-major): U = W*x ----------------
__global__ void k_matmul_plain(const float* __restrict__ X, const float* __restrict__ W,
                               float* __restrict__ U,
                               int N, int Cin, int Cout, long batchStride, long sliceOff) {
    int j = blockIdx.y % 3;
    int ot = blockIdx.y / 3;
    int b = blockIdx.z;
    int o0 = ot * OT;
    int tid = threadIdx.x;
    int n = blockIdx.x * 256 + tid;

    __shared__ float wsm[OT][176];  // Cin <= 169
    for (int t = tid; t < OT * Cin; t += 256) {
        int oo = t / Cin, c = t % Cin;
        int o = o0 + oo;
        wsm[oo][c] = (o < Cout) ? W[(size_t)o * Cin + c] : 0.f;
    }
    __syncthreads();

    const float* Xp = X + (size_t)b * batchStride + sliceOff + (size_t)j * N + n;
    float au[OT];
#pragma unroll
    for (int oo = 0; oo < OT; ++oo) au[oo] = 0.f;

    for (int c = 0; c < Cin; ++c) {
        float xv = Xp[(size_t)c * 3 * N];
#pragma unroll
        for (int oo = 0; oo < OT; ++oo) au[oo] += wsm[oo][c] * xv;
    }
#pragma unroll
    for (int oo = 0; oo < OT; ++oo) {
        int o = o0 + oo;
        if (o < Cout) U[(((size_t)b * Cout + o) * 3 + j) * N + n] = au[oo];
    }
}

// ---------------- layer-5 stats (deterministic): one block per channel ----------------
__global__ void k_stats_plain_det(const float* __restrict__ U, float* __restrict__ mv,
                                  int N, int Cout, int BN, float cnt) {
    int o = blockIdx.x;
    int tid = threadIdx.x;
    float s1 = 0.f, s2 = 0.f;
    for (int g = tid; g < BN; g += 256) {
        int b = g / N, n = g % N;
        const float* Ub = U + (((size_t)b * Cout + o) * 3) * N;
        float p0 = Ub[n], p1 = Ub[(size_t)N + n], p2 = Ub[(size_t)2 * N + n];
        float nm = sqrtf(p0 * p0 + p1 * p1 + p2 * p2) + EPSV;
        s1 += nm;
        s2 += nm * nm;
    }
    __shared__ float r1[256], r2[256];
    r1[tid] = s1; r2[tid] = s2;
    __syncthreads();
    for (int st = 128; st > 0; st >>= 1) {
        if (tid < st) { r1[tid] += r1[tid + st]; r2[tid] += r2[tid + st]; }
        __syncthreads();
    }
    if (tid == 0) {
        float mu = r1[0] / cnt;
        float var = r2[0] / cnt - mu * mu;
        mv[2 * o] = mu;
        mv[2 * o + 1] = rsqrtf(var + 1e-5f);
    }
}

// ---------------- layer-5 final: BN + dir leaky (1 dir channel) -> d_out ----------------
__global__ void k_final_plain(const float* __restrict__ U, const float* __restrict__ Dv,
                              const float* __restrict__ mv,
                              const float* __restrict__ gamma, const float* __restrict__ beta,
                              float* __restrict__ out, int N, int Cout) {
    int b = blockIdx.z, o = blockIdx.y, tid = threadIdx.x;
    int n = blockIdx.x * 256 + tid;
    float mu = mv[2 * o];
    float inv = mv[2 * o + 1];
    float g = gamma[o], bt = beta[o];

    const float* Ub = U + (((size_t)b * Cout + o) * 3) * N;
    float p0 = Ub[n], p1 = Ub[(size_t)N + n], p2 = Ub[(size_t)2 * N + n];
    float nm = sqrtf(p0 * p0 + p1 * p1 + p2 * p2) + EPSV;
    float nbn = (nm - mu) * inv * g + bt;
    float sc = nbn / nm;
    p0 *= sc; p1 *= sc; p2 *= sc;

    float d0 = Dv[((size_t)b * 3 + 0) * N + n];
    float d1 = Dv[((size_t)b * 3 + 1) * N + n];
    float d2 = Dv[((size_t)b * 3 + 2) * N + n];
    float dot = p0 * d0 + p1 * d1 + p2 * d2;
    float o0, o1, o2;
    if (dot >= 0.f) {
        o0 = p0; o1 = p1; o2 = p2;
    } else {
        float f = dot / (d0 * d0 + d1 * d1 + d2 * d2 + EPSV);
        o0 = NS * p0 + (1.f - NS) * (p0 - f * d0);
        o1 = NS * p1 + (1.f - NS) * (p1 - f * d1);
        o2 = NS * p2 + (1.f - NS) * (p2 - f * d2);
    }
    size_t ob = (((size_t)b * Cout + o) * 3) * N + n;
    out[ob] = o0;
    out[ob + (size_t)N] = o1;
    out[ob + (size_t)2 * N] = o2;
}

extern "C" void kernel_launch(void* const* d_in, const int* in_sizes, int n_in,
                              void* d_out, int out_size, void* d_ws, size_t ws_size,
                              hipStream_t stream) {
    (void)in_sizes; (void)n_in; (void)out_size; (void)ws_size;
    const int B = 8, N = 1024;

    const float* x = (const float*)d_in[0];
    const float* W[5]; const float* Dw[5]; const float* G[5]; const float* Bt[5];
    for (int l = 0; l < 5; ++l) {
        W[l]  = (const float*)d_in[1 + 4 * l];
        Dw[l] = (const float*)d_in[2 + 4 * l];
        G[l]  = (const float*)d_in[3 + 4 * l];
        Bt[l] = (const float*)d_in[4 + 4 * l];
    }

    float* ws = (float*)d_ws;
    size_t off = 0;
    float* xt = ws + off;     off += (size_t)B * 3 * N;
    float* xx = ws + off;     off += (size_t)B * N;
    int* idx = (int*)(ws + off); off += (size_t)B * N * KNN;
    float* catp = ws + off;   off += (size_t)B * N * CROW;
    float* catn = ws + off;   off += (size_t)B * N * CROW;
    float* Up = ws + off;     off += (size_t)B * N * 85 * 3;
    float* Vp = ws + off;     off += (size_t)B * N * 85 * 3;
    float* UDp = ws + off;    off += (size_t)B * N * 85 * 3;
    float* VDp = ws + off;    off += (size_t)B * N * 85 * 3;
    float* U5 = ws + off;     off += (size_t)B * 341 * 3 * N;
    float* d5buf = ws + off;  off += (size_t)B * 3 * N;
    float* partials = ws + off; off += (size_t)341 * SSPLIT * 2;
    float* mv = ws + off;     off += 2 * 341;

    k_transpose<<<(B * N + 255) / 256, 256, 0, stream>>>(x, xt, B, N);

    const int Cin_[4]  = {1, 21, 21, 42};
    const int Cout_[4] = {21, 21, 42, 85};
    const int inOff_[4] = {-1, 0, 21, 42};
    const int outOff_[4] = {0, 21, 42, 84};
    const int Tile_[4] = {32, 32, 32, 8};   // LDS budget: L4 needs small x-tile

    const int BN = B * N;

    for (int l = 0; l < 4; ++l) {
        int C = Cin_[l], Co = Cout_[l];
        int D = C * 3;
        int CoP = (Co + 3) & ~3;
        int TILE = Tile_[l];

        // n-major source for sqnorm/knn
        const float* Xn; long bs, so;
        if (inOff_[l] < 0) { Xn = xt; bs = (long)3 * N; so = 0; }
        else { Xn = catn; bs = (long)CROW * N; so = (long)inOff_[l] * 3 * N; }

        // point-major source for matmul
        const float* Xp; int rs, co;
        if (inOff_[l] < 0) { Xp = x; rs = 3; co = 0; }
        else { Xp = catp; rs = CROW; co = inOff_[l] * 3; }

        k_sqnorm<<<(B * N + 255) / 256, 256, 0, stream>>>(Xn, xx, B, N, D, bs, so);

        dim3 gk(N / QK, B);
        k_knn<<<gk, 256, 0, stream>>>(Xn, xx, idx, N, D, bs, so);

        size_t smemB = (size_t)(4 * C * CoP + TILE * C * 3) * sizeof(float);
        k_matmul_pair_lds<<<(B * N) / TILE, 256, smemB, stream>>>(
            Xp, W[l], Dw[l], Up, Vp, UDp, VDp, C, Co, CoP, TILE, rs, co);

        dim3 gst(Co, SSPLIT);
        k_stats_edge_det<<<gst, 256, 0, stream>>>(Up, Vp, idx, partials, N, Co, BN);
        k_stats_reduce<<<(Co + 255) / 256, 256, 0, stream>>>(
            partials, mv, Co, (float)((size_t)BN * KNN));

        int total = BN * Co;
        k_final_edge_p<<<(total + 255) / 256, 256, 0, stream>>>(
            Up, Vp, UDp, VDp, idx, mv, G[l], Bt[l], catp,
            N, Co, outOff_[l] * 3, total);

        int CC = Co * 3;
        dim3 gt(N / 32, (CC + 31) / 32, B);
        k_transpose_cat<<<gt, 256, 0, stream>>>(catp, catn, N, outOff_[l] * 3, CC);
    }

    // layer 5 (reads catn n-major)
    {
        long bs = (long)CROW * N, so = 0;
        dim3 gm5(N / 256, 3 * ((341 + OT - 1) / OT), B);
        k_matmul_plain<<<gm5, 256, 0, stream>>>(catn, W[4], U5, N, 169, 341, bs, so);
        dim3 gmd(N / 256, 3, B);
        k_matmul_plain<<<gmd, 256, 0, stream>>>(catn, Dw[4], d5buf, N, 169, 1, bs, so);
        k_stats_plain_det<<<341, 256, 0, stream>>>(U5, mv, N, 341, BN, (float)BN);
        dim3 gs5(N / 256, 341, B);
        k_final_plain<<<gs5, 256, 0, stream>>>(U5, d5buf, mv, G[4], Bt[4],
                                               (float*)d_out, N, 341);
    }
}

// Round 11
// 739.249 us; speedup vs baseline: 1.0964x; 1.0964x over previous
//
#include <hip/hip_runtime.h>
#include <math.h>

#define KNN 20
#define NS 0.2f
#define EPSV 1e-6f
#define QT 4
#define OT 8
#define CROW 507   // 169*3, cat row stride (floats)
#define SSPLIT 8   // stats splits (== B; split s covers batch s exactly)

extern __shared__ __align__(16) float smem[];

// ---------------- transpose (B,N,3) -> (B,3,N) (layer-1 knn input) ----------------
__global__ void k_transpose(const float* __restrict__ x, float* __restrict__ xt,
                            int B, int N) {
    int i = blockIdx.x * blockDim.x + threadIdx.x;
    if (i >= B * N) return;
    int b = i / N, n = i % N;
    const float* src = x + (size_t)(b * N + n) * 3;
    float* dst = xt + (size_t)b * 3 * N + n;
    dst[0] = src[0];
    dst[(size_t)N] = src[1];
    dst[(size_t)2 * N] = src[2];
}

// ---------------- knn with fused sqnorm: 4 waves/block, wave-local top-k ----------------
// xm2/qn accumulated in the same ascending-d chains as the old k_sqnorm -> bitwise
// identical to the xx loads; pd expression unchanged; selection verbatim R8.
__global__ void k_knn(const float* __restrict__ X, int* __restrict__ idx,
                      int N, int D, long batchStride, long sliceOff) {
    int b = blockIdx.y;
    int q0 = blockIdx.x * QT;
    int tid = threadIdx.x;
    int lane = tid & 63;
    int wave = tid >> 6;

    __shared__ __align__(16) float qf[128 * QT];   // [d][q], D <= 126
    __shared__ __align__(16) float pd[QT][1024];   // N == 1024

    const float* Xb = X + (size_t)b * batchStride + sliceOff;

    for (int t = tid; t < QT * D; t += 256) {
        int d = t >> 2, q = t & 3;
        qf[d * QT + q] = Xb[(size_t)d * N + (q0 + q)];
    }
    __syncthreads();

    float a0x = 0.f, a0y = 0.f, a0z = 0.f, a0w = 0.f;
    float a1x = 0.f, a1y = 0.f, a1z = 0.f, a1w = 0.f;
    float a2x = 0.f, a2y = 0.f, a2z = 0.f, a2w = 0.f;
    float a3x = 0.f, a3y = 0.f, a3z = 0.f, a3w = 0.f;
    float m2x = 0.f, m2y = 0.f, m2z = 0.f, m2w = 0.f;   // ||x_m||^2, 4 m's
    float qn0 = 0.f, qn1 = 0.f, qn2 = 0.f, qn3 = 0.f;   // ||x_q||^2, 4 q's

    const float* mbase = Xb + 4 * tid;
#pragma unroll 3
    for (int d = 0; d < D; ++d) {
        float4 xm = *(const float4*)(mbase + (size_t)d * N);
        float4 qv = *(const float4*)(qf + d * QT);
        a0x += qv.x * xm.x; a0y += qv.x * xm.y; a0z += qv.x * xm.z; a0w += qv.x * xm.w;
        a1x += qv.y * xm.x; a1y += qv.y * xm.y; a1z += qv.y * xm.z; a1w += qv.y * xm.w;
        a2x += qv.z * xm.x; a2y += qv.z * xm.y; a2z += qv.z * xm.z; a2w += qv.z * xm.w;
        a3x += qv.w * xm.x; a3y += qv.w * xm.y; a3z += qv.w * xm.z; a3w += qv.w * xm.w;
        m2x += xm.x * xm.x; m2y += xm.y * xm.y; m2z += xm.z * xm.z; m2w += xm.w * xm.w;
        qn0 += qv.x * qv.x; qn1 += qv.y * qv.y; qn2 += qv.z * qv.z; qn3 += qv.w * qv.w;
    }

    {
        float4 v;
        v.x = 2.f * a0x - qn0 - m2x; v.y = 2.f * a0y - qn0 - m2y;
        v.z = 2.f * a0z - qn0 - m2z; v.w = 2.f * a0w - qn0 - m2w;
        *(float4*)&pd[0][4 * tid] = v;
        v.x = 2.f * a1x - qn1 - m2x; v.y = 2.f * a1y - qn1 - m2y;
        v.z = 2.f * a1z - qn1 - m2z; v.w = 2.f * a1w - qn1 - m2w;
        *(float4*)&pd[1][4 * tid] = v;
        v.x = 2.f * a2x - qn2 - m2x; v.y = 2.f * a2y - qn2 - m2y;
        v.z = 2.f * a2z - qn2 - m2z; v.w = 2.f * a2w - qn2 - m2w;
        *(float4*)&pd[2][4 * tid] = v;
        v.x = 2.f * a3x - qn3 - m2x; v.y = 2.f * a3y - qn3 - m2y;
        v.z = 2.f * a3z - qn3 - m2z; v.w = 2.f * a3w - qn3 - m2w;
        *(float4*)&pd[3][4 * tid] = v;
    }
    __syncthreads();

    // selection: verbatim iterative argmax (bit-identical indices)
    float v[16];
#pragma unroll
    for (int t = 0; t < 16; ++t) v[t] = pd[wave][t * 64 + lane];

    long outBase = ((long)b * N + q0 + wave) * KNN;
    for (int it = 0; it < KNN; ++it) {
        float bv = v[0];
        int bi = lane;
#pragma unroll
        for (int t = 1; t < 16; ++t) {
            if (v[t] > bv) { bv = v[t]; bi = t * 64 + lane; }
        }
#pragma unroll
        for (int off = 32; off >= 1; off >>= 1) {
            float ov = __shfl_xor(bv, off, 64);
            int oi = __shfl_xor(bi, off, 64);
            if (ov > bv || (ov == bv && oi < bi)) { bv = ov; bi = oi; }
        }
        if (lane == 0) idx[outBase + it] = bi;
#pragma unroll
        for (int t = 0; t < 16; ++t) {
            if (bi == t * 64 + lane) v[t] = -INFINITY;
        }
    }
}

// ---------------- LDS-staged point-major pair matmul ----------------
__global__ void k_matmul_pair_lds(const float* __restrict__ X, const float* __restrict__ W,
                                  const float* __restrict__ Dw,
                                  float* __restrict__ U, float* __restrict__ V,
                                  float* __restrict__ UD, float* __restrict__ VD,
                                  int C, int Co, int CoP, int TILE,
                                  int rowStride, int colOff) {
    const int CP = C * CoP;
    float* wts = smem;            // 4*CP: [WA | WB-WA | DA | DB-DA], each [c][o]
    float* xs = smem + 4 * CP;    // TILE * C * 3

    int tid = threadIdx.x;
    int bn0 = blockIdx.x * TILE;  // flattened b*N+n base
    int C3 = C * 3;

    // zero padded o-lanes
    int npad = CoP - Co;
    if (npad) {
        for (int t = tid; t < 4 * C * npad; t += 256) {
            int q = t / npad, oo = Co + t % npad;
            int mat = q / C, c = q % C;
            wts[mat * CP + c * CoP + oo] = 0.f;
        }
    }
    // stage raw weights (coalesced global reads, LDS transpose writes)
    int twoCC = 2 * C * Co;
    for (int t = tid; t < twoCC; t += 256) {
        int o = t / (2 * C), c = t % (2 * C);
        float w = W[t], dw = Dw[t];
        if (c < C) {
            wts[c * CoP + o] = w;
            wts[2 * CP + c * CoP + o] = dw;
        } else {
            wts[CP + (c - C) * CoP + o] = w;
            wts[3 * CP + (c - C) * CoP + o] = dw;
        }
    }
    // stage point rows (coalesced)
    for (int t = tid; t < TILE * C3; t += 256) {
        int p = t / C3, cc = t % C3;
        xs[t] = X[(size_t)(bn0 + p) * rowStride + colOff + cc];
    }
    __syncthreads();
    // WB -= WA, DB -= DA in place
    for (int t = tid; t < CP; t += 256) {
        wts[CP + t] -= wts[t];
        wts[3 * CP + t] -= wts[2 * CP + t];
    }
    __syncthreads();

    int GPP = CoP >> 2;
    int items = TILE * GPP;
    for (int e = tid; e < items; e += 256) {
        int p = e / GPP, og = e - p * GPP;
        int o0 = og * 4;
        const float* xr = xs + p * C3;

        float aU[4][3], aV[4][3], aDu[4][3], aDv[4][3];
#pragma unroll
        for (int i = 0; i < 4; ++i)
#pragma unroll
            for (int j = 0; j < 3; ++j) {
                aU[i][j] = 0.f; aV[i][j] = 0.f; aDu[i][j] = 0.f; aDv[i][j] = 0.f;
            }

        for (int c = 0; c < C; ++c) {
            float x0 = xr[c * 3], x1 = xr[c * 3 + 1], x2 = xr[c * 3 + 2];
            const float* wp = wts + c * CoP + o0;
            float4 wa4 = *(const float4*)(wp);
            float4 wb4 = *(const float4*)(wp + CP);
            float4 da4 = *(const float4*)(wp + 2 * CP);
            float4 db4 = *(const float4*)(wp + 3 * CP);
            float wav[4] = {wa4.x, wa4.y, wa4.z, wa4.w};
            float wbv[4] = {wb4.x, wb4.y, wb4.z, wb4.w};
            float dav[4] = {da4.x, da4.y, da4.z, da4.w};
            float dbv[4] = {db4.x, db4.y, db4.z, db4.w};
#pragma unroll
            for (int i = 0; i < 4; ++i) {
                aU[i][0] += wav[i] * x0; aU[i][1] += wav[i] * x1; aU[i][2] += wav[i] * x2;
                aV[i][0] += wbv[i] * x0; aV[i][1] += wbv[i] * x1; aV[i][2] += wbv[i] * x2;
                aDu[i][0] += dav[i] * x0; aDu[i][1] += dav[i] * x1; aDu[i][2] += dav[i] * x2;
                aDv[i][0] += dbv[i] * x0; aDv[i][1] += dbv[i] * x1; aDv[i][2] += dbv[i] * x2;
            }
        }

        size_t base = ((size_t)(bn0 + p) * Co + o0) * 3;
#pragma unroll
        for (int i = 0; i < 4; ++i) {
            int o = o0 + i;
            if (o < Co) {
                size_t off = base + (size_t)i * 3;
                U[off] = aU[i][0]; U[off + 1] = aU[i][1]; U[off + 2] = aU[i][2];
                V[off] = aV[i][0]; V[off + 1] = aV[i][1]; V[off + 2] = aV[i][2];
                UD[off] = aDu[i][0]; UD[off + 1] = aDu[i][1]; UD[off + 2] = aDu[i][2];
                VD[off] = aDv[i][0]; VD[off + 1] = aDv[i][1]; VD[off + 2] = aDv[i][2];
            }
        }
    }
}

// ---------------- BN stats stage A (deterministic, R5 order + LDS staging) ----------------
__global__ void k_stats_edge_det(const float* __restrict__ U, const float* __restrict__ V,
                                 const int* __restrict__ idx, float* __restrict__ partials,
                                 int N, int Co, int BN) {
    int o = blockIdx.x;
    int s = blockIdx.y;
    int tid = threadIdx.x;
    int P = BN / SSPLIT;      // == N == 1024
    int g0 = s * P;

    __shared__ float Ush[3072];   // N * 3 (channel-o vectors for batch s)
    __shared__ float r1[256], r2[256];

    for (int t = tid; t < P; t += 256) {
        const float* Ur = U + ((size_t)(g0 + t) * Co + o) * 3;
        Ush[t * 3 + 0] = Ur[0];
        Ush[t * 3 + 1] = Ur[1];
        Ush[t * 3 + 2] = Ur[2];
    }
    __syncthreads();

    float s1 = 0.f, s2 = 0.f;
    for (int pl = tid; pl < P; pl += 256) {
        int g = g0 + pl;                       // flattened b*N+n
        const float* Vr = V + ((size_t)g * Co + o) * 3;
        float v0 = Vr[0], v1 = Vr[1], v2 = Vr[2];
        const int* ip = idx + (size_t)g * KNN;
        for (int kk = 0; kk < KNN; ++kk) {
            const float* Ur = Ush + ip[kk] * 3;   // idx is batch-local
            float p0 = Ur[0] + v0;
            float p1 = Ur[1] + v1;
            float p2 = Ur[2] + v2;
            float nm = sqrtf(p0 * p0 + p1 * p1 + p2 * p2) + EPSV;
            s1 += nm;
            s2 += nm * nm;
        }
    }
    r1[tid] = s1; r2[tid] = s2;
    __syncthreads();
    for (int st = 128; st > 0; st >>= 1) {
        if (tid < st) { r1[tid] += r1[tid + st]; r2[tid] += r2[tid + st]; }
        __syncthreads();
    }
    if (tid == 0) {
        partials[(o * SSPLIT + s) * 2] = r1[0];
        partials[(o * SSPLIT + s) * 2 + 1] = r2[0];
    }
}

// ---------------- BN + dir leaky + mean-pool (fused stage-B), thread per (b,n,o) ----------------
// mv computed inline from partials with the identical fixed-order sum and
// mu/var/rsqrt expressions as the old k_stats_reduce -> bit-identical.
__global__ void k_final_edge_p(const float* __restrict__ U, const float* __restrict__ V,
                               const float* __restrict__ UD, const float* __restrict__ VD,
                               const int* __restrict__ idx, const float* __restrict__ partials,
                               const float* __restrict__ gamma, const float* __restrict__ beta,
                               float* __restrict__ catp,
                               int N, int Co, int colOff, float cnt, int total) {
    int g = blockIdx.x * 256 + threadIdx.x;
    if (g >= total) return;
    int o = g % Co;
    int r = g / Co;
    int n = r % N;
    int b = r / N;

    float s1 = 0.f, s2 = 0.f;
    for (int s = 0; s < SSPLIT; ++s) {
        s1 += partials[(o * SSPLIT + s) * 2];
        s2 += partials[(o * SSPLIT + s) * 2 + 1];
    }
    float mu = s1 / cnt;
    float var = s2 / cnt - mu * mu;
    float inv = rsqrtf(var + 1e-5f);
    float gmm = gamma[o], bt = beta[o];

    size_t ctr = ((size_t)(b * N + n) * Co + o) * 3;
    float v0 = V[ctr], v1 = V[ctr + 1], v2 = V[ctr + 2];
    float w0 = VD[ctr], w1 = VD[ctr + 1], w2 = VD[ctr + 2];
    const int* ip = idx + ((size_t)b * N + n) * KNN;

    float a0 = 0.f, a1 = 0.f, a2 = 0.f;
    for (int kk = 0; kk < KNN; ++kk) {
        int m = ip[kk];
        size_t nb = ((size_t)(b * N + m) * Co + o) * 3;
        float p0 = U[nb] + v0;
        float p1 = U[nb + 1] + v1;
        float p2 = U[nb + 2] + v2;
        float nm = sqrtf(p0 * p0 + p1 * p1 + p2 * p2) + EPSV;
        float nbn = (nm - mu) * inv * gmm + bt;
        float sc = nbn / nm;
        p0 *= sc; p1 *= sc; p2 *= sc;
        float d0 = UD[nb] + w0;
        float d1 = UD[nb + 1] + w1;
        float d2 = UD[nb + 2] + w2;
        float dot = p0 * d0 + p1 * d1 + p2 * d2;
        if (dot >= 0.f) {
            a0 += p0; a1 += p1; a2 += p2;
        } else {
            float f = dot / (d0 * d0 + d1 * d1 + d2 * d2 + EPSV);
            a0 += NS * p0 + (1.f - NS) * (p0 - f * d0);
            a1 += NS * p1 + (1.f - NS) * (p1 - f * d1);
            a2 += NS * p2 + (1.f - NS) * (p2 - f * d2);
        }
    }
    const float invk = 1.f / (float)KNN;
    float* outp = catp + (size_t)(b * N + n) * CROW + colOff + o * 3;
    outp[0] = a0 * invk;
    outp[1] = a1 * invk;
    outp[2] = a2 * invk;
}

// ---------------- cat_p slice -> cat_n slice (LDS tiled transpose) ----------------
__global__ void k_transpose_cat(const float* __restrict__ catp, float* __restrict__ catn,
                                int N, int c0, int CC) {
    __shared__ float tile[32][33];
    int b = blockIdx.z;
    int n0 = blockIdx.x * 32;
    int cb = blockIdx.y * 32;
    int tid = threadIdx.x;
    int tx = tid & 31, ty = tid >> 5;   // 32 x 8

#pragma unroll
    for (int rr = 0; rr < 4; ++rr) {
        int nl = ty + rr * 8;
        int c = cb + tx;
        if (c < CC)
            tile[nl][tx] = catp[(size_t)(b * N + n0 + nl) * CROW + c0 + c];
    }
    __syncthreads();
#pragma unroll
    for (int rr = 0; rr < 4; ++rr) {
        int cl = ty + rr * 8;
        int c = cb + cl;
        if (c < CC)
            catn[(size_t)b * CROW * N + (size_t)(c0 + c) * N + n0 + tx] = tile[tx][cl];
    }
}

// ---------------- plain matmul (layer 5, n-major): U = W*x ----------------
__global__ void k_matmul_plain(const float* __restrict__ X, const float* __restrict__ W,
                               float* __restrict__ U,
                               int N, int Cin, int Cout, long batchStride, long sliceOff) {
    int j = blockIdx.y % 3;
    int ot = blockIdx.y / 3;
    int b = blockIdx.z;
    int o0 = ot * OT;
    int tid = threadIdx.x;
    int n = blockIdx.x * 256 + tid;

    __shared__ float wsm[OT][176];  // Cin <= 169
    for (int t = tid; t < OT * Cin; t += 256) {
        int oo = t / Cin, c = t % Cin;
        int o = o0 + oo;
        wsm[oo][c] = (o < Cout) ? W[(size_t)o * Cin + c] : 0.f;
    }
    __syncthreads();

    const float* Xp = X + (size_t)b * batchStride + sliceOff + (size_t)j * N + n;
    float au[OT];
#pragma unroll
    for (int oo = 0; oo < OT; ++oo) au[oo] = 0.f;

    for (int c = 0; c < Cin; ++c) {
        float xv = Xp[(size_t)c * 3 * N];
#pragma unroll
        for (int oo = 0; oo < OT; ++oo) au[oo] += wsm[oo][c] * xv;
    }
#pragma unroll
    for (int oo = 0; oo < OT; ++oo) {
        int o = o0 + oo;
        if (o < Cout) U[(((size_t)b * Cout + o) * 3 + j) * N + n] = au[oo];
    }
}

// ---------------- layer-5 stats (deterministic): one block per channel ----------------
__global__ void k_stats_plain_det(const float* __restrict__ U, float* __restrict__ mv,
                                  int N, int Cout, int BN, float cnt) {
    int o = blockIdx.x;
    int tid = threadIdx.x;
    float s1 = 0.f, s2 = 0.f;
    for (int g = tid; g < BN; g += 256) {
        int b = g / N, n = g % N;
        const float* Ub = U + (((size_t)b * Cout + o) * 3) * N;
        float p0 = Ub[n], p1 = Ub[(size_t)N + n], p2 = Ub[(size_t)2 * N + n];
        float nm = sqrtf(p0 * p0 + p1 * p1 + p2 * p2) + EPSV;
        s1 += nm;
        s2 += nm * nm;
    }
    __shared__ float r1[256], r2[256];
    r1[tid] = s1; r2[tid] = s2;
    __syncthreads();
    for (int st = 128; st > 0; st >>= 1) {
        if (tid < st) { r1[tid] += r1[tid + st]; r2[tid] += r2[tid + st]; }
        __syncthreads();
    }
    if (tid == 0) {
        float mu = r1[0] / cnt;
        float var = r2[0] / cnt - mu * mu;
        mv[2 * o] = mu;
        mv[2 * o + 1] = rsqrtf(var + 1e-5f);
    }
}

// ---------------- layer-5 final: BN + dir leaky (1 dir channel) -> d_out ----------------
__global__ void k_final_plain(const float* __restrict__ U, const float* __restrict__ Dv,
                              const float* __restrict__ mv,
                              const float* __restrict__ gamma, const float* __restrict__ beta,
                              float* __restrict__ out, int N, int Cout) {
    int b = blockIdx.z, o = blockIdx.y, tid = threadIdx.x;
    int n = blockIdx.x * 256 + tid;
    float mu = mv[2 * o];
    float inv = mv[2 * o + 1];
    float g = gamma[o], bt = beta[o];

    const float* Ub = U + (((size_t)b * Cout + o) * 3) * N;
    float p0 = Ub[n], p1 = Ub[(size_t)N + n], p2 = Ub[(size_t)2 * N + n];
    float nm = sqrtf(p0 * p0 + p1 * p1 + p2 * p2) + EPSV;
    float nbn = (nm - mu) * inv * g + bt;
    float sc = nbn / nm;
    p0 *= sc; p1 *= sc; p2 *= sc;

    float d0 = Dv[((size_t)b * 3 + 0) * N + n];
    float d1 = Dv[((size_t)b * 3 + 1) * N + n];
    float d2 = Dv[((size_t)b * 3 + 2) * N + n];
    float dot = p0 * d0 + p1 * d1 + p2 * d2;
    float o0, o1, o2;
    if (dot >= 0.f) {
        o0 = p0; o1 = p1; o2 = p2;
    } else {
        float f = dot / (d0 * d0 + d1 * d1 + d2 * d2 + EPSV);
        o0 = NS * p0 + (1.f - NS) * (p0 - f * d0);
        o1 = NS * p1 + (1.f - NS) * (p1 - f * d1);
        o2 = NS * p2 + (1.f - NS) * (p2 - f * d2);
    }
    size_t ob = (((size_t)b * Cout + o) * 3) * N + n;
    out[ob] = o0;
    out[ob + (size_t)N] = o1;
    out[ob + (size_t)2 * N] = o2;
}

extern "C" void kernel_launch(void* const* d_in, const int* in_sizes, int n_in,
                              void* d_out, int out_size, void* d_ws, size_t ws_size,
                              hipStream_t stream) {
    (void)in_sizes; (void)n_in; (void)out_size; (void)ws_size;
    const int B = 8, N = 1024;

    const float* x = (const float*)d_in[0];
    const float* W[5]; const float* Dw[5]; const float* G[5]; const float* Bt[5];
    for (int l = 0; l < 5; ++l) {
        W[l]  = (const float*)d_in[1 + 4 * l];
        Dw[l] = (const float*)d_in[2 + 4 * l];
        G[l]  = (const float*)d_in[3 + 4 * l];
        Bt[l] = (const float*)d_in[4 + 4 * l];
    }

    float* ws = (float*)d_ws;
    size_t off = 0;
    float* xt = ws + off;     off += (size_t)B * 3 * N;
    int* idx = (int*)(ws + off); off += (size_t)B * N * KNN;
    float* catp = ws + off;   off += (size_t)B * N * CROW;
    float* catn = ws + off;   off += (size_t)B * N * CROW;
    float* Up = ws + off;     off += (size_t)B * N * 85 * 3;
    float* Vp = ws + off;     off += (size_t)B * N * 85 * 3;
    float* UDp = ws + off;    off += (size_t)B * N * 85 * 3;
    float* VDp = ws + off;    off += (size_t)B * N * 85 * 3;
    float* U5 = ws + off;     off += (size_t)B * 341 * 3 * N;
    float* d5buf = ws + off;  off += (size_t)B * 3 * N;
    float* partials = ws + off; off += (size_t)341 * SSPLIT * 2;
    float* mv = ws + off;     off += 2 * 341;

    k_transpose<<<(B * N + 255) / 256, 256, 0, stream>>>(x, xt, B, N);

    const int Cin_[4]  = {1, 21, 21, 42};
    const int Cout_[4] = {21, 21, 42, 85};
    const int inOff_[4] = {-1, 0, 21, 42};
    const int outOff_[4] = {0, 21, 42, 84};
    const int Tile_[4] = {32, 32, 32, 8};   // LDS budget: L4 needs small x-tile

    const int BN = B * N;

    for (int l = 0; l < 4; ++l) {
        int C = Cin_[l], Co = Cout_[l];
        int D = C * 3;
        int CoP = (Co + 3) & ~3;
        int TILE = Tile_[l];

        // n-major source for knn
        const float* Xn; long bs, so;
        if (inOff_[l] < 0) { Xn = xt; bs = (long)3 * N; so = 0; }
        else { Xn = catn; bs = (long)CROW * N; so = (long)inOff_[l] * 3 * N; }

        // point-major source for matmul
        const float* Xp; int rs, co;
        if (inOff_[l] < 0) { Xp = x; rs = 3; co = 0; }
        else { Xp = catp; rs = CROW; co = inOff_[l] * 3; }

        dim3 gk(N / QT, B);
        k_knn<<<gk, 256, 0, stream>>>(Xn, idx, N, D, bs, so);

        size_t smemB = (size_t)(4 * C * CoP + TILE * C * 3) * sizeof(float);
        k_matmul_pair_lds<<<(B * N) / TILE, 256, smemB, stream>>>(
            Xp, W[l], Dw[l], Up, Vp, UDp, VDp, C, Co, CoP, TILE, rs, co);

        dim3 gst(Co, SSPLIT);
        k_stats_edge_det<<<gst, 256, 0, stream>>>(Up, Vp, idx, partials, N, Co, BN);

        int total = BN * Co;
        k_final_edge_p<<<(total + 255) / 256, 256, 0, stream>>>(
            Up, Vp, UDp, VDp, idx, partials, G[l], Bt[l], catp,
            N, Co, outOff_[l] * 3, (float)((size_t)BN * KNN), total);

        int CC = Co * 3;
        dim3 gt(N / 32, (CC + 31) / 32, B);
        k_transpose_cat<<<gt, 256, 0, stream>>>(catp, catn, N, outOff_[l] * 3, CC);
    }

    // layer 5 (reads catn n-major)
    {
        long bs = (long)CROW * N, so = 0;
        dim3 gm5(N / 256, 3 * ((341 + OT - 1) / OT), B);
        k_matmul_plain<<<gm5, 256, 0, stream>>>(catn, W[4], U5, N, 169, 341, bs, so);
        dim3 gmd(N / 256, 3, B);
        k_matmul_plain<<<gmd, 256, 0, stream>>>(catn, Dw[4], d5buf, N, 169, 1, bs, so);
        k_stats_plain_det<<<341, 256, 0, stream>>>(U5, mv, N, 341, BN, (float)BN);
        dim3 gs5(N / 256, 341, B);
        k_final_plain<<<gs5, 256, 0, stream>>>(U5, d5buf, mv, G[4], Bt[4],
                                               (float*)d_out, N, 341);
    }
}